// Round 11
// baseline (593.156 us; speedup 1.0000x reference)
//
#include <hip/hip_runtime.h>

typedef __attribute__((ext_vector_type(8))) short bf16x8;
typedef __attribute__((ext_vector_type(4))) float f32x4;

#define AS1 __attribute__((address_space(1)))
#define AS3 __attribute__((address_space(3)))

#if defined(__has_builtin)
#  if __has_builtin(__builtin_amdgcn_exp2f)
#    define EXP2F(x) __builtin_amdgcn_exp2f(x)
#  endif
#endif
#ifndef EXP2F
#  define EXP2F(x) __builtin_exp2f(x)
#endif

// Raw barriers that do NOT drain the async prefetch queue (unlike __syncthreads,
// which emits s_waitcnt vmcnt(0) lgkmcnt(0) and kills the pipeline).
#define BAR_WAIT_VM8  asm volatile("s_waitcnt vmcnt(8)\ns_barrier" ::: "memory")
#define BAR_WAIT_VM4  asm volatile("s_waitcnt vmcnt(4)\ns_barrier" ::: "memory")
#define BAR_WAIT_VM2  asm volatile("s_waitcnt vmcnt(2)\ns_barrier" ::: "memory")
#define BAR_WAIT_VM0  asm volatile("s_waitcnt vmcnt(0)\ns_barrier" ::: "memory")
#define BAR_WAIT_LGKM asm volatile("s_waitcnt lgkmcnt(0)\ns_barrier" ::: "memory")

// gfx950 dual-swap lane exchanges (both operands updated):
//   permlane32: a' = [a.lo32 | b.lo32], b' = [a.hi32 | b.hi32]
//   permlane16: 16-lane rows: a' = [a.r0, b.r0, a.r2, b.r2], b' = [a.r1, b.r1, a.r3, b.r3]
#define PL32(a, b) asm("v_permlane32_swap_b32 %0, %1" : "+v"(a), "+v"(b))
#define PL16(a, b) asm("v_permlane16_swap_b32 %0, %1" : "+v"(a), "+v"(b))

__device__ __forceinline__ unsigned short f2bf(float f) {
    union { float f; unsigned u; } v; v.f = f;
    unsigned r = v.u + 0x7fffu + ((v.u >> 16) & 1u);   // RNE
    return (unsigned short)(r >> 16);
}

// Async 16B/lane global->LDS DMA. lds dst must be wave-uniform base (+lane*16).
__device__ __forceinline__ void dma16(const void* g, void* l) {
    __builtin_amdgcn_global_load_lds((const AS1 unsigned int*)g,
                                     (AS3 unsigned int*)l, 16, 0, 0);
}

// fp32 -> bf16 bulk convert, up to 3 regions, optional scale. 8 elems/thread.
__global__ __launch_bounds__(256) void convert_regions(
    const float* __restrict__ s0, unsigned short* __restrict__ d0, int n0, float c0,
    const float* __restrict__ s1, unsigned short* __restrict__ d1, int n1, float c1,
    const float* __restrict__ s2, unsigned short* __restrict__ d2, int n2, float c2)
{
    long long e = ((long long)blockIdx.x * 256 + threadIdx.x) * 8;
    const float* s; unsigned short* d; float sc;
    if (e < n0) { s = s0; d = d0; sc = c0; }
    else { e -= n0;
    if (e < n1) { s = s1; d = d1; sc = c1; }
    else { e -= n1;
    if (e < n2) { s = s2; d = d2; sc = c2; } else return; } }
    const float4 f0 = *(const float4*)(s + e);
    const float4 f1 = *(const float4*)(s + e + 4);
    union { unsigned short u[8]; uint4 q; } t;
    t.u[0]=f2bf(f0.x*sc); t.u[1]=f2bf(f0.y*sc); t.u[2]=f2bf(f0.z*sc); t.u[3]=f2bf(f0.w*sc);
    t.u[4]=f2bf(f1.x*sc); t.u[5]=f2bf(f1.y*sc); t.u[6]=f2bf(f1.z*sc); t.u[7]=f2bf(f1.w*sc);
    *(uint4*)(d + e) = t.q;
}

// ---------------------------------------------------------------------------
// GEMM 128x128 (out-projection): C = A[M,K] * B[N,K]^T + bias, fp32 out.
// 4 waves (2x2), 4x4 16x16x32 MFMA/wave, global_load_lds staging,
// XOR-swizzled unpadded LDS, double-buffered raw-barrier K-loop
// (vmcnt(8) keeps prefetch in flight; lgkm read-fence only at end).
// LDS 64 KB -> 2 blocks/CU. NO min-waves launch_bounds (spill cliff).
// ---------------------------------------------------------------------------
__global__ __launch_bounds__(256) void gemm128_bias(
    const unsigned short* __restrict__ A, const unsigned short* __restrict__ B,
    float* __restrict__ C0, const float* __restrict__ bias, int M, int N, int K)
{
    __shared__ __align__(16) unsigned short smem[2 * 16384];

    const int tid  = threadIdx.x;
    const int wq   = tid >> 6;
    const int lane = tid & 63;
    const int l16  = lane & 15;
    const int quad = lane >> 4;
    const int m0   = blockIdx.x * 128;
    const int n0   = blockIdx.y * 128;
    const int lr   = lane >> 3;
    const int cs   = lane & 7;

    f32x4 acc[4][4];
#pragma unroll
    for (int mt = 0; mt < 4; ++mt)
#pragma unroll
        for (int nt = 0; nt < 4; ++nt) acc[mt][nt] = (f32x4){0.f, 0.f, 0.f, 0.f};

    auto issue = [&](int buf, int kk) {
        unsigned short* as = smem + buf * 16384;
        unsigned short* bs = as + 8192;
#pragma unroll
        for (int i = 0; i < 4; ++i) {
            const int rr = (wq * 4 + i) * 8 + lr;
            const int cg = cs ^ (rr & 7);
            dma16(A + (size_t)(m0 + rr) * K + kk + cg * 8, as + (wq * 4 + i) * 512);
            dma16(B + (size_t)(n0 + rr) * K + kk + cg * 8, bs + (wq * 4 + i) * 512);
        }
    };

    const int nIt = K >> 6;
    issue(0, 0);
#pragma unroll 2
    for (int it = 0; it < nIt; ++it) {
        const int cur = it & 1;
        if (it + 1 < nIt) {
            issue(cur ^ 1, (it + 1) << 6);
            BAR_WAIT_VM8;
        } else {
            BAR_WAIT_VM0;
        }
        const unsigned short* as = smem + cur * 16384;
        const unsigned short* bs = as + 8192;
#pragma unroll
        for (int ch = 0; ch < 2; ++ch) {
            const int swz = (((ch * 4 + quad) ^ (l16 & 7)) * 8);
            bf16x8 aF[4], bF[4];
#pragma unroll
            for (int mt = 0; mt < 4; ++mt)
                aF[mt] = *(const bf16x8*)(as + ((wq >> 1) * 64 + mt * 16 + l16) * 64 + swz);
#pragma unroll
            for (int nt = 0; nt < 4; ++nt)
                bF[nt] = *(const bf16x8*)(bs + ((wq & 1) * 64 + nt * 16 + l16) * 64 + swz);
#pragma unroll
            for (int mt = 0; mt < 4; ++mt)
#pragma unroll
                for (int nt = 0; nt < 4; ++nt)
                    acc[mt][nt] = __builtin_amdgcn_mfma_f32_16x16x32_bf16(
                        aF[mt], bF[nt], acc[mt][nt], 0, 0, 0);
        }
        BAR_WAIT_LGKM;
    }

    const int wr = wq >> 1, wc = wq & 1;
#pragma unroll
    for (int mt = 0; mt < 4; ++mt)
#pragma unroll
    for (int nt = 0; nt < 4; ++nt) {
        const int coln = n0 + wc * 64 + nt * 16 + l16;
        const float bv = bias ? bias[coln] : 0.f;
#pragma unroll
        for (int r = 0; r < 4; ++r) {
            const int rowm = m0 + wr * 64 + mt * 16 + quad * 4 + r;
            C0[(size_t)rowm * N + coln] = acc[mt][nt][r] + bv;
        }
    }
}

// ---------------------------------------------------------------------------
// ROUND 11 (= R10 with the d_out cast fixed; R10 was a host-side compile
// error, no hardware verdict): GEMM 256x256 (fused QKV projection).
// Mechanical 2x scale-up of the PROVEN gemm128 loop — same raw-barrier/
// vmcnt(8) pipeline (8 DMAs/wave/tile holds exactly), same XOR swizzle,
// same read pattern — chosen because the 128^2 structure is STAGING-
// BANDWIDTH-bound: bytes-staged/FLOP halves at 256^2 (15.2 -> 7.6 B/KFLOP),
// the same economy that takes the guide's ladder from 912 to 1563-1728 TF.
// (Full 8-phase schedule deliberately NOT ported — one proven lever/round.)
// 512 threads = 8 waves (2M x 4N); wave owns 128x64 = 8x4 16x16x32 frags
// (acc 128 VGPR, ~210 total -> 2 waves/SIMD). LDS 2 x (A 32KB | B 32KB) =
// 128 KB -> 1 block/CU. Grid dim3(32,12) = 384 blocks (25% tail imbalance
// accepted). NO min-waves launch_bounds (R7/round-8 spill cliff).
// Epilogue over N=3072: cols 0..1023 -> Q [bh][n][e] (C0), 1024..2047 -> K
// (C1), 2048..3071 -> V^T [bh][e][n] (C2, transposed tile via mfma(bF,aF)).
// ---------------------------------------------------------------------------
__global__ __launch_bounds__(512) void gemm256_qkv(
    const unsigned short* __restrict__ A, const unsigned short* __restrict__ B,
    unsigned short* __restrict__ C0, unsigned short* __restrict__ C1,
    unsigned short* __restrict__ C2, int M, int N, int K)
{
    __shared__ __align__(16) unsigned short smem[2 * 32768];   // 128 KB

    const int tid  = threadIdx.x;
    const int wq   = tid >> 6;          // 0..7
    const int lane = tid & 63;
    const int l16  = lane & 15;
    const int quad = lane >> 4;
    const int m0   = blockIdx.x * 256;
    const int n0   = blockIdx.y * 256;
    const int lr   = lane >> 3;
    const int cs   = lane & 7;
    const int wr   = wq >> 2;           // 0..1 (M half)
    const int wc   = wq & 3;            // 0..3 (N quarter)
    const bool vswap = (n0 >= 2048);

    f32x4 acc[8][4];
#pragma unroll
    for (int mt = 0; mt < 8; ++mt)
#pragma unroll
        for (int nt = 0; nt < 4; ++nt) acc[mt][nt] = (f32x4){0.f, 0.f, 0.f, 0.f};

    // Stage A[256x64] + B[256x64] (32 KB each): 8 waves x 4 chunks x 8 rows.
    auto issue = [&](int buf, int kk) {
        unsigned short* as = smem + buf * 32768;
        unsigned short* bs = as + 16384;
#pragma unroll
        for (int i = 0; i < 4; ++i) {
            const int rr = (wq * 4 + i) * 8 + lr;       // 0..255
            const int cg = cs ^ (rr & 7);
            dma16(A + (size_t)(m0 + rr) * K + kk + cg * 8, as + (wq * 4 + i) * 512);
            dma16(B + (size_t)(n0 + rr) * K + kk + cg * 8, bs + (wq * 4 + i) * 512);
        }
    };

    const int nIt = K >> 6;
    issue(0, 0);
#pragma unroll 2
    for (int it = 0; it < nIt; ++it) {
        const int cur = it & 1;
        if (it + 1 < nIt) {
            issue(cur ^ 1, (it + 1) << 6);
            BAR_WAIT_VM8;       // waits only current tile's 8 DMAs/wave
        } else {
            BAR_WAIT_VM0;
        }
        const unsigned short* as = smem + cur * 32768;
        const unsigned short* bs = as + 16384;
#pragma unroll
        for (int ch = 0; ch < 2; ++ch) {
            const int swz = (((ch * 4 + quad) ^ (l16 & 7)) * 8);
            bf16x8 aF[8], bF[4];
#pragma unroll
            for (int mt = 0; mt < 8; ++mt)
                aF[mt] = *(const bf16x8*)(as + (wr * 128 + mt * 16 + l16) * 64 + swz);
#pragma unroll
            for (int nt = 0; nt < 4; ++nt)
                bF[nt] = *(const bf16x8*)(bs + (wc * 64 + nt * 16 + l16) * 64 + swz);
            if (vswap) {
#pragma unroll
                for (int mt = 0; mt < 8; ++mt)
#pragma unroll
                    for (int nt = 0; nt < 4; ++nt)
                        acc[mt][nt] = __builtin_amdgcn_mfma_f32_16x16x32_bf16(
                            bF[nt], aF[mt], acc[mt][nt], 0, 0, 0);
            } else {
#pragma unroll
                for (int mt = 0; mt < 8; ++mt)
#pragma unroll
                    for (int nt = 0; nt < 4; ++nt)
                        acc[mt][nt] = __builtin_amdgcn_mfma_f32_16x16x32_bf16(
                            aF[mt], bF[nt], acc[mt][nt], 0, 0, 0);
            }
        }
        BAR_WAIT_LGKM;
    }

    if (!vswap) {
        // Q (cols<1024) / K (1024..2047): [bh][n][e]
#pragma unroll
        for (int mt = 0; mt < 8; ++mt)
#pragma unroll
        for (int nt = 0; nt < 4; ++nt) {
            const int coln = n0 + wc * 64 + nt * 16 + l16;
            unsigned short* dst = (coln < 1024) ? C0 : C1;
            const int h = (coln >> 6) & 15, e = coln & 63;
#pragma unroll
            for (int r = 0; r < 4; ++r) {
                const int rowm = m0 + wr * 128 + mt * 16 + quad * 4 + r;
                const int b = rowm >> 11, n = rowm & 2047;
                dst[(((size_t)(b * 16 + h) * 2048 + n) << 6) + e] = f2bf(acc[mt][nt][r]);
            }
        }
    } else {
        // V^T: acc holds transposed tile; rows = V-cols (e), cols = tokens.
#pragma unroll
        for (int mt = 0; mt < 8; ++mt)
#pragma unroll
        for (int nt = 0; nt < 4; ++nt) {
#pragma unroll
            for (int r = 0; r < 4; ++r) {
                const int eg = n0 + wc * 64 + nt * 16 + quad * 4 + r;  // 2048..3071
                const int h = (eg >> 6) - 32, e = eg & 63;
                const int rowm = m0 + wr * 128 + mt * 16 + l16;
                const int b = rowm >> 11, n = rowm & 2047;
                C2[((size_t)(b * 16 + h) * 64 + e) * 2048 + n] = f2bf(acc[mt][nt][r]);
            }
        }
    }
}

// ---------------------------------------------------------------------------
// Flash attention — R9 version (best measured: 74.8 us). R3 structure +
// T5 setprio around the two MFMA clusters (+5.3% verified, m191-consistent).
// Q,K: [bh][n][e] bf16 (Q pre-scaled by 0.125*log2e); V: [bh][e][n] bf16.
// O: [b*n][1024] bf16. Block = 512 threads = 8 waves x 32 q-rows.
// Double-buffered raw-barrier K/V staging (vmcnt(2)); Ps LDS eliminated
// (in-register PL32/PL16 relayout); LDS 32 KB.
// ---------------------------------------------------------------------------
__global__ __launch_bounds__(512, 4) void attn_kernel(
    const unsigned short* __restrict__ Q, const unsigned short* __restrict__ K,
    const unsigned short* __restrict__ V, unsigned short* __restrict__ O)
{
    __shared__ __align__(16) unsigned short KVs[2 * 8192];  // [buf][Ks 4096|Vt 4096]

    const int tid  = threadIdx.x;
    const int q0   = blockIdx.x * 256;
    const int bh   = blockIdx.y;
    const int wq   = tid >> 6;          // 0..7
    const int lane = tid & 63;
    const int l16  = lane & 15;
    const int quad = lane >> 4;
    const int lr   = lane >> 3;
    const int cs   = lane & 7;
    const int swl  = l16 & 7;           // row-XOR for the K/V tile swizzle

    const unsigned short* Qg = Q + (size_t)bh * 2048 * 64;
    const unsigned short* Kg = K + (size_t)bh * 2048 * 64;
    const unsigned short* Vg = V + (size_t)bh * 64 * 2048;

    bf16x8 bQ[2][2];
#pragma unroll
    for (int sub = 0; sub < 2; ++sub)
#pragma unroll
        for (int ch = 0; ch < 2; ++ch)
            bQ[sub][ch] = *(const bf16x8*)(Qg + (size_t)(q0 + wq * 32 + sub * 16 + l16) * 64
                                           + ch * 32 + quad * 8);

    bf16x8 ones;
#pragma unroll
    for (int i = 0; i < 8; ++i) ones[i] = (short)0x3F80;  // bf16 1.0

    f32x4 o[2][4], lf[2];
#pragma unroll
    for (int s = 0; s < 2; ++s) {
        lf[s] = (f32x4){0.f, 0.f, 0.f, 0.f};
#pragma unroll
        for (int e = 0; e < 4; ++e) o[s][e] = (f32x4){0.f, 0.f, 0.f, 0.f};
    }

    auto issueKV = [&](int buf, int key0) {
        unsigned short* ks = KVs + buf * 8192;
        unsigned short* vt = ks + 4096;
#pragma unroll
        for (int i = 0; i < 2; ++i) {
            const int j  = wq * 2 + i;          // 0..15
            const int rr = (j & 7) * 8 + lr;
            const int cg = cs ^ (rr & 7);
            if (j < 8)
                dma16(Kg + (size_t)(key0 + rr) * 64 + cg * 8, ks + (j & 7) * 512);
            else
                dma16(Vg + (size_t)rr * 2048 + key0 + cg * 8, vt + (j & 7) * 512);
        }
    };

    issueKV(0, 0);
#pragma unroll 2
    for (int kt = 0; kt < 32; ++kt) {
        const int cur = kt & 1;
        if (kt + 1 < 32) {
            issueKV(cur ^ 1, (kt + 1) * 64);
            BAR_WAIT_VM2;
        } else {
            BAR_WAIT_VM0;
        }
        const unsigned short* ks = KVs + cur * 8192;
        const unsigned short* vt = ks + 4096;

        // S^T = K Q^T : D[m=key][n=q]  (logits pre-scaled via Q)
        f32x4 s[2][4];
#pragma unroll
        for (int sub = 0; sub < 2; ++sub)
#pragma unroll
            for (int c = 0; c < 4; ++c) s[sub][c] = (f32x4){0.f, 0.f, 0.f, 0.f};
        __builtin_amdgcn_s_setprio(1);
#pragma unroll
        for (int ch = 0; ch < 2; ++ch) {
            const int swz = ((ch * 4 + quad) ^ swl) * 8;
#pragma unroll
            for (int c = 0; c < 4; ++c) {
                const bf16x8 aK = *(const bf16x8*)(ks + (c * 16 + l16) * 64 + swz);
#pragma unroll
                for (int sub = 0; sub < 2; ++sub)
                    s[sub][c] = __builtin_amdgcn_mfma_f32_16x16x32_bf16(
                        aK, bQ[sub][ch], s[sub][c], 0, 0, 0);
            }
        }
        __builtin_amdgcn_s_setprio(0);

        // p = 2^s (raw v_exp_f32); trunc-pack pairs (v_perm) to bf16 dwords,
        // then route S^T-layout -> PV A-fragment fully in-register.
        bf16x8 aP[2][2];
#pragma unroll
        for (int sub = 0; sub < 2; ++sub) {
            unsigned pkx[4], pky[4];
#pragma unroll
            for (int c = 0; c < 4; ++c) {
                const float p0 = EXP2F(s[sub][c][0]);
                const float p1 = EXP2F(s[sub][c][1]);
                const float p2 = EXP2F(s[sub][c][2]);
                const float p3 = EXP2F(s[sub][c][3]);
                pkx[c] = __builtin_amdgcn_perm(__float_as_uint(p1), __float_as_uint(p0), 0x07060302);
                pky[c] = __builtin_amdgcn_perm(__float_as_uint(p3), __float_as_uint(p2), 0x07060302);
            }
#pragma unroll
            for (int cc = 0; cc < 2; ++cc) {
                unsigned dx = pkx[cc * 2], ex = pkx[cc * 2 + 1];
                unsigned dy = pky[cc * 2], ey = pky[cc * 2 + 1];
                PL32(dx, ex); PL32(dy, ey);
                PL16(dx, ex); PL16(dy, ey);
                union { unsigned u[4]; bf16x8 v; } t;
                t.u[0] = dx; t.u[1] = dy; t.u[2] = ex; t.u[3] = ey;
                aP[sub][cc] = t.v;
            }
        }

        // O += P V ; l += P 1 (denominator on the MFMA pipe).
        __builtin_amdgcn_s_setprio(1);
#pragma unroll
        for (int cc = 0; cc < 2; ++cc) {
            const int swz = ((cc * 4 + quad) ^ swl) * 8;
#pragma unroll
            for (int sub = 0; sub < 2; ++sub)
                lf[sub] = __builtin_amdgcn_mfma_f32_16x16x32_bf16(aP[sub][cc], ones, lf[sub], 0, 0, 0);
#pragma unroll
            for (int et = 0; et < 4; ++et) {
                const bf16x8 bV = *(const bf16x8*)(vt + (et * 16 + l16) * 64 + swz);
#pragma unroll
                for (int sub = 0; sub < 2; ++sub)
                    o[sub][et] = __builtin_amdgcn_mfma_f32_16x16x32_bf16(
                        aP[sub][cc], bV, o[sub][et], 0, 0, 0);
            }
        }
        __builtin_amdgcn_s_setprio(0);
        BAR_WAIT_LGKM;   // all waves' ks/vt reads done before next DMA overwrites cur
    }

    // l sits in C-layout: lf[sub][r] is the denom for q-row quad*4+r (all l16).
    const int bb = bh >> 4, hh = bh & 15;
#pragma unroll
    for (int sub = 0; sub < 2; ++sub) {
#pragma unroll
        for (int r = 0; r < 4; ++r) {
            const float linv = 1.0f / lf[sub][r];
            const int qrow = q0 + wq * 32 + sub * 16 + quad * 4 + r;
#pragma unroll
            for (int et = 0; et < 4; ++et) {
                O[(size_t)(bb * 2048 + qrow) * 1024 + hh * 64 + et * 16 + l16] =
                    f2bf(o[sub][et][r] * linv);
            }
        }
    }
}

extern "C" void kernel_launch(void* const* d_in, const int* in_sizes, int n_in,
                              void* d_out, int out_size, void* d_ws, size_t ws_size,
                              hipStream_t stream) {
    const float* x     = (const float*)d_in[0];
    const float* w_q   = (const float*)d_in[1];
    const float* w_kv  = (const float*)d_in[2];
    const float* w_out = (const float*)d_in[3];
    const float* b_out = (const float*)d_in[4];
    const float CEXP = 0.125f * 1.44269504f;   // attn scale * log2(e), folded into w_q
    const size_t MB = 1024 * 1024;

    // ws (64 MB): Qw@0 16 | Kw@16 16 | Vw@32 16 | Ow@48 16   (all bf16)
    // d_out (32 MB fp32, dead until final GEMM): xb@0 16 | wqkvb@16 6 (bf16).
    // wob (w_out bf16, 2 MB) -> dead Qw region AFTER attn.
    unsigned short* Qw    = (unsigned short*)d_ws;
    unsigned short* Kw    = (unsigned short*)((char*)d_ws + 16 * MB);
    unsigned short* Vw    = (unsigned short*)((char*)d_ws + 32 * MB);
    unsigned short* Ow    = (unsigned short*)((char*)d_ws + 48 * MB);
    unsigned short* xb    = (unsigned short*)d_out;
    unsigned short* wqkvb = (unsigned short*)((char*)d_out + 16 * MB);
    unsigned short* wob   = Qw;

    // Convert x + packed [w_q (pre-scaled); w_kv] to bf16 in d_out scratch.
    convert_regions<<<5632, 256, 0, stream>>>(
        x, xb, 8388608, 1.0f,
        w_q, wqkvb, 1048576, CEXP,
        w_kv, wqkvb + (size_t)1048576, 2097152, 1.0f);

    // Fused QKV projection: 256^2 tile, 512 threads, dim3(32,12) = 384 blocks.
    gemm256_qkv<<<dim3(32, 12), 512, 0, stream>>>(
        xb, wqkvb, Qw, Kw, Vw, 8192, 3072, 1024);

    // Attention: 512 blocks dim3(8,64), 512 threads (8 waves x 32 q).
    attn_kernel<<<dim3(8, 64), 512, 0, stream>>>(Qw, Kw, Vw, Ow);

    // w_out -> bf16 into dead Qw region.
    convert_regions<<<512, 256, 0, stream>>>(
        w_out, wob, 1048576, 1.0f,
        nullptr, nullptr, 0, 0.f, nullptr, nullptr, 0, 0.f);

    // Out projection, 128^2 tile (proven), dim3 grid; writes fp32 d_out.
    gemm128_bias<<<dim3(64, 8), 256, 0, stream>>>(
        Ow, wob, (float*)d_out, b_out, 8192, 1024, 1024);
}

// Round 12
// 591.511 us; speedup vs baseline: 1.0028x; 1.0028x over previous
//
#include <hip/hip_runtime.h>

typedef __attribute__((ext_vector_type(8))) short bf16x8;
typedef __attribute__((ext_vector_type(4))) float f32x4;

#define AS1 __attribute__((address_space(1)))
#define AS3 __attribute__((address_space(3)))

#if defined(__has_builtin)
#  if __has_builtin(__builtin_amdgcn_exp2f)
#    define EXP2F(x) __builtin_amdgcn_exp2f(x)
#  endif
#endif
#ifndef EXP2F
#  define EXP2F(x) __builtin_exp2f(x)
#endif

// Raw barriers that do NOT drain the async prefetch queue (unlike __syncthreads,
// which emits s_waitcnt vmcnt(0) lgkmcnt(0) and kills the pipeline).
#define BAR_WAIT_VM8  asm volatile("s_waitcnt vmcnt(8)\ns_barrier" ::: "memory")
#define BAR_WAIT_VM4  asm volatile("s_waitcnt vmcnt(4)\ns_barrier" ::: "memory")
#define BAR_WAIT_VM2  asm volatile("s_waitcnt vmcnt(2)\ns_barrier" ::: "memory")
#define BAR_WAIT_VM0  asm volatile("s_waitcnt vmcnt(0)\ns_barrier" ::: "memory")
#define BAR_WAIT_LGKM asm volatile("s_waitcnt lgkmcnt(0)\ns_barrier" ::: "memory")

// gfx950 dual-swap lane exchanges (both operands updated):
//   permlane32: a' = [a.lo32 | b.lo32], b' = [a.hi32 | b.hi32]
//   permlane16: 16-lane rows: a' = [a.r0, b.r0, a.r2, b.r2], b' = [a.r1, b.r1, a.r3, b.r3]
#define PL32(a, b) asm("v_permlane32_swap_b32 %0, %1" : "+v"(a), "+v"(b))
#define PL16(a, b) asm("v_permlane16_swap_b32 %0, %1" : "+v"(a), "+v"(b))

__device__ __forceinline__ unsigned short f2bf(float f) {
    union { float f; unsigned u; } v; v.f = f;
    unsigned r = v.u + 0x7fffu + ((v.u >> 16) & 1u);   // RNE
    return (unsigned short)(r >> 16);
}

// Async 16B/lane global->LDS DMA. lds dst must be wave-uniform base (+lane*16).
__device__ __forceinline__ void dma16(const void* g, void* l) {
    __builtin_amdgcn_global_load_lds((const AS1 unsigned int*)g,
                                     (AS3 unsigned int*)l, 16, 0, 0);
}

// fp32 -> bf16 bulk convert, up to 3 regions, optional scale. 8 elems/thread.
__global__ __launch_bounds__(256) void convert_regions(
    const float* __restrict__ s0, unsigned short* __restrict__ d0, int n0, float c0,
    const float* __restrict__ s1, unsigned short* __restrict__ d1, int n1, float c1,
    const float* __restrict__ s2, unsigned short* __restrict__ d2, int n2, float c2)
{
    long long e = ((long long)blockIdx.x * 256 + threadIdx.x) * 8;
    const float* s; unsigned short* d; float sc;
    if (e < n0) { s = s0; d = d0; sc = c0; }
    else { e -= n0;
    if (e < n1) { s = s1; d = d1; sc = c1; }
    else { e -= n1;
    if (e < n2) { s = s2; d = d2; sc = c2; } else return; } }
    const float4 f0 = *(const float4*)(s + e);
    const float4 f1 = *(const float4*)(s + e + 4);
    union { unsigned short u[8]; uint4 q; } t;
    t.u[0]=f2bf(f0.x*sc); t.u[1]=f2bf(f0.y*sc); t.u[2]=f2bf(f0.z*sc); t.u[3]=f2bf(f0.w*sc);
    t.u[4]=f2bf(f1.x*sc); t.u[5]=f2bf(f1.y*sc); t.u[6]=f2bf(f1.z*sc); t.u[7]=f2bf(f1.w*sc);
    *(uint4*)(d + e) = t.q;
}

// ---------------------------------------------------------------------------
// GEMM 128x128 (out-projection): C = A[M,K] * B[N,K]^T + bias, fp32 out.
// 4 waves (2x2), 4x4 16x16x32 MFMA/wave, global_load_lds staging,
// XOR-swizzled unpadded LDS, double-buffered raw-barrier K-loop
// (vmcnt(8) keeps prefetch in flight; lgkm read-fence only at end).
// LDS 64 KB -> 2 blocks/CU. NO min-waves launch_bounds (spill cliff).
// ---------------------------------------------------------------------------
__global__ __launch_bounds__(256) void gemm128_bias(
    const unsigned short* __restrict__ A, const unsigned short* __restrict__ B,
    float* __restrict__ C0, const float* __restrict__ bias, int M, int N, int K)
{
    __shared__ __align__(16) unsigned short smem[2 * 16384];

    const int tid  = threadIdx.x;
    const int wq   = tid >> 6;
    const int lane = tid & 63;
    const int l16  = lane & 15;
    const int quad = lane >> 4;
    const int m0   = blockIdx.x * 128;
    const int n0   = blockIdx.y * 128;
    const int lr   = lane >> 3;
    const int cs   = lane & 7;

    f32x4 acc[4][4];
#pragma unroll
    for (int mt = 0; mt < 4; ++mt)
#pragma unroll
        for (int nt = 0; nt < 4; ++nt) acc[mt][nt] = (f32x4){0.f, 0.f, 0.f, 0.f};

    auto issue = [&](int buf, int kk) {
        unsigned short* as = smem + buf * 16384;
        unsigned short* bs = as + 8192;
#pragma unroll
        for (int i = 0; i < 4; ++i) {
            const int rr = (wq * 4 + i) * 8 + lr;
            const int cg = cs ^ (rr & 7);
            dma16(A + (size_t)(m0 + rr) * K + kk + cg * 8, as + (wq * 4 + i) * 512);
            dma16(B + (size_t)(n0 + rr) * K + kk + cg * 8, bs + (wq * 4 + i) * 512);
        }
    };

    const int nIt = K >> 6;
    issue(0, 0);
#pragma unroll 2
    for (int it = 0; it < nIt; ++it) {
        const int cur = it & 1;
        if (it + 1 < nIt) {
            issue(cur ^ 1, (it + 1) << 6);
            BAR_WAIT_VM8;
        } else {
            BAR_WAIT_VM0;
        }
        const unsigned short* as = smem + cur * 16384;
        const unsigned short* bs = as + 8192;
#pragma unroll
        for (int ch = 0; ch < 2; ++ch) {
            const int swz = (((ch * 4 + quad) ^ (l16 & 7)) * 8);
            bf16x8 aF[4], bF[4];
#pragma unroll
            for (int mt = 0; mt < 4; ++mt)
                aF[mt] = *(const bf16x8*)(as + ((wq >> 1) * 64 + mt * 16 + l16) * 64 + swz);
#pragma unroll
            for (int nt = 0; nt < 4; ++nt)
                bF[nt] = *(const bf16x8*)(bs + ((wq & 1) * 64 + nt * 16 + l16) * 64 + swz);
#pragma unroll
            for (int mt = 0; mt < 4; ++mt)
#pragma unroll
                for (int nt = 0; nt < 4; ++nt)
                    acc[mt][nt] = __builtin_amdgcn_mfma_f32_16x16x32_bf16(
                        aF[mt], bF[nt], acc[mt][nt], 0, 0, 0);
        }
        BAR_WAIT_LGKM;
    }

    const int wr = wq >> 1, wc = wq & 1;
#pragma unroll
    for (int mt = 0; mt < 4; ++mt)
#pragma unroll
    for (int nt = 0; nt < 4; ++nt) {
        const int coln = n0 + wc * 64 + nt * 16 + l16;
        const float bv = bias ? bias[coln] : 0.f;
#pragma unroll
        for (int r = 0; r < 4; ++r) {
            const int rowm = m0 + wr * 64 + mt * 16 + quad * 4 + r;
            C0[(size_t)rowm * N + coln] = acc[mt][nt][r] + bv;
        }
    }
}

// ---------------------------------------------------------------------------
// ROUND 12 (= R11 with the register cap FIXED): GEMM 256x256 (fused QKV).
// R11 verdict: the structure is sound (passed) but the compiler's DEFAULT
// occupancy heuristic for a 512-thread block capped the allocator at 128
// VGPRs -> acc spilled to scratch (WRITE_SIZE 930 MB, MfmaUtil 4.8%,
// 426 us). The kernel needs ~210 VGPRs (acc 128 + aF 32 + bF 16 + addr).
// FIX: __launch_bounds__(512, 2) — min 2 waves/EU is exactly what the
// 8-wave block with 128 KB LDS (1 block/CU) occupies anyway, and raises
// the VGPR cap to 512/2 = 256/wave. No occupancy is sacrificed that the
// LDS footprint hadn't already spent.
// Staging-economy rationale unchanged: bytes-staged/FLOP halves vs 128^2
// (15.2 -> 7.6 B/KFLOP) on the staging-bandwidth-bound proven loop.
// 512 threads = 8 waves (2M x 4N); wave owns 128x64 = 8x4 16x16x32 frags.
// Grid dim3(32,12) = 384 blocks. Epilogue over N=3072: cols 0..1023 -> Q
// [bh][n][e] (C0), 1024..2047 -> K (C1), 2048..3071 -> V^T [bh][e][n]
// (C2, transposed tile via mfma(bF,aF)).
// ---------------------------------------------------------------------------
__global__ __launch_bounds__(512, 2) void gemm256_qkv(
    const unsigned short* __restrict__ A, const unsigned short* __restrict__ B,
    unsigned short* __restrict__ C0, unsigned short* __restrict__ C1,
    unsigned short* __restrict__ C2, int M, int N, int K)
{
    __shared__ __align__(16) unsigned short smem[2 * 32768];   // 128 KB

    const int tid  = threadIdx.x;
    const int wq   = tid >> 6;          // 0..7
    const int lane = tid & 63;
    const int l16  = lane & 15;
    const int quad = lane >> 4;
    const int m0   = blockIdx.x * 256;
    const int n0   = blockIdx.y * 256;
    const int lr   = lane >> 3;
    const int cs   = lane & 7;
    const int wr   = wq >> 2;           // 0..1 (M half)
    const int wc   = wq & 3;            // 0..3 (N quarter)
    const bool vswap = (n0 >= 2048);

    f32x4 acc[8][4];
#pragma unroll
    for (int mt = 0; mt < 8; ++mt)
#pragma unroll
        for (int nt = 0; nt < 4; ++nt) acc[mt][nt] = (f32x4){0.f, 0.f, 0.f, 0.f};

    // Stage A[256x64] + B[256x64] (32 KB each): 8 waves x 4 chunks x 8 rows.
    auto issue = [&](int buf, int kk) {
        unsigned short* as = smem + buf * 32768;
        unsigned short* bs = as + 16384;
#pragma unroll
        for (int i = 0; i < 4; ++i) {
            const int rr = (wq * 4 + i) * 8 + lr;       // 0..255
            const int cg = cs ^ (rr & 7);
            dma16(A + (size_t)(m0 + rr) * K + kk + cg * 8, as + (wq * 4 + i) * 512);
            dma16(B + (size_t)(n0 + rr) * K + kk + cg * 8, bs + (wq * 4 + i) * 512);
        }
    };

    const int nIt = K >> 6;
    issue(0, 0);
#pragma unroll 2
    for (int it = 0; it < nIt; ++it) {
        const int cur = it & 1;
        if (it + 1 < nIt) {
            issue(cur ^ 1, (it + 1) << 6);
            BAR_WAIT_VM8;       // waits only current tile's 8 DMAs/wave
        } else {
            BAR_WAIT_VM0;
        }
        const unsigned short* as = smem + cur * 32768;
        const unsigned short* bs = as + 16384;
#pragma unroll
        for (int ch = 0; ch < 2; ++ch) {
            const int swz = (((ch * 4 + quad) ^ (l16 & 7)) * 8);
            bf16x8 aF[8], bF[4];
#pragma unroll
            for (int mt = 0; mt < 8; ++mt)
                aF[mt] = *(const bf16x8*)(as + (wr * 128 + mt * 16 + l16) * 64 + swz);
#pragma unroll
            for (int nt = 0; nt < 4; ++nt)
                bF[nt] = *(const bf16x8*)(bs + (wc * 64 + nt * 16 + l16) * 64 + swz);
            if (vswap) {
#pragma unroll
                for (int mt = 0; mt < 8; ++mt)
#pragma unroll
                    for (int nt = 0; nt < 4; ++nt)
                        acc[mt][nt] = __builtin_amdgcn_mfma_f32_16x16x32_bf16(
                            bF[nt], aF[mt], acc[mt][nt], 0, 0, 0);
            } else {
#pragma unroll
                for (int mt = 0; mt < 8; ++mt)
#pragma unroll
                    for (int nt = 0; nt < 4; ++nt)
                        acc[mt][nt] = __builtin_amdgcn_mfma_f32_16x16x32_bf16(
                            aF[mt], bF[nt], acc[mt][nt], 0, 0, 0);
            }
        }
        BAR_WAIT_LGKM;
    }

    if (!vswap) {
        // Q (cols<1024) / K (1024..2047): [bh][n][e]
#pragma unroll
        for (int mt = 0; mt < 8; ++mt)
#pragma unroll
        for (int nt = 0; nt < 4; ++nt) {
            const int coln = n0 + wc * 64 + nt * 16 + l16;
            unsigned short* dst = (coln < 1024) ? C0 : C1;
            const int h = (coln >> 6) & 15, e = coln & 63;
#pragma unroll
            for (int r = 0; r < 4; ++r) {
                const int rowm = m0 + wr * 128 + mt * 16 + quad * 4 + r;
                const int b = rowm >> 11, n = rowm & 2047;
                dst[(((size_t)(b * 16 + h) * 2048 + n) << 6) + e] = f2bf(acc[mt][nt][r]);
            }
        }
    } else {
        // V^T: acc holds transposed tile; rows = V-cols (e), cols = tokens.
#pragma unroll
        for (int mt = 0; mt < 8; ++mt)
#pragma unroll
        for (int nt = 0; nt < 4; ++nt) {
#pragma unroll
            for (int r = 0; r < 4; ++r) {
                const int eg = n0 + wc * 64 + nt * 16 + quad * 4 + r;  // 2048..3071
                const int h = (eg >> 6) - 32, e = eg & 63;
                const int rowm = m0 + wr * 128 + mt * 16 + l16;
                const int b = rowm >> 11, n = rowm & 2047;
                C2[((size_t)(b * 16 + h) * 64 + e) * 2048 + n] = f2bf(acc[mt][nt][r]);
            }
        }
    }
}

// ---------------------------------------------------------------------------
// Flash attention — R9 version (best measured: 74.8 us). R3 structure +
// T5 setprio around the two MFMA clusters (+5.3% verified, m191-consistent).
// Q,K: [bh][n][e] bf16 (Q pre-scaled by 0.125*log2e); V: [bh][e][n] bf16.
// O: [b*n][1024] bf16. Block = 512 threads = 8 waves x 32 q-rows.
// Double-buffered raw-barrier K/V staging (vmcnt(2)); Ps LDS eliminated
// (in-register PL32/PL16 relayout); LDS 32 KB.
// ---------------------------------------------------------------------------
__global__ __launch_bounds__(512, 4) void attn_kernel(
    const unsigned short* __restrict__ Q, const unsigned short* __restrict__ K,
    const unsigned short* __restrict__ V, unsigned short* __restrict__ O)
{
    __shared__ __align__(16) unsigned short KVs[2 * 8192];  // [buf][Ks 4096|Vt 4096]

    const int tid  = threadIdx.x;
    const int q0   = blockIdx.x * 256;
    const int bh   = blockIdx.y;
    const int wq   = tid >> 6;          // 0..7
    const int lane = tid & 63;
    const int l16  = lane & 15;
    const int quad = lane >> 4;
    const int lr   = lane >> 3;
    const int cs   = lane & 7;
    const int swl  = l16 & 7;           // row-XOR for the K/V tile swizzle

    const unsigned short* Qg = Q + (size_t)bh * 2048 * 64;
    const unsigned short* Kg = K + (size_t)bh * 2048 * 64;
    const unsigned short* Vg = V + (size_t)bh * 64 * 2048;

    bf16x8 bQ[2][2];
#pragma unroll
    for (int sub = 0; sub < 2; ++sub)
#pragma unroll
        for (int ch = 0; ch < 2; ++ch)
            bQ[sub][ch] = *(const bf16x8*)(Qg + (size_t)(q0 + wq * 32 + sub * 16 + l16) * 64
                                           + ch * 32 + quad * 8);

    bf16x8 ones;
#pragma unroll
    for (int i = 0; i < 8; ++i) ones[i] = (short)0x3F80;  // bf16 1.0

    f32x4 o[2][4], lf[2];
#pragma unroll
    for (int s = 0; s < 2; ++s) {
        lf[s] = (f32x4){0.f, 0.f, 0.f, 0.f};
#pragma unroll
        for (int e = 0; e < 4; ++e) o[s][e] = (f32x4){0.f, 0.f, 0.f, 0.f};
    }

    auto issueKV = [&](int buf, int key0) {
        unsigned short* ks = KVs + buf * 8192;
        unsigned short* vt = ks + 4096;
#pragma unroll
        for (int i = 0; i < 2; ++i) {
            const int j  = wq * 2 + i;          // 0..15
            const int rr = (j & 7) * 8 + lr;
            const int cg = cs ^ (rr & 7);
            if (j < 8)
                dma16(Kg + (size_t)(key0 + rr) * 64 + cg * 8, ks + (j & 7) * 512);
            else
                dma16(Vg + (size_t)rr * 2048 + key0 + cg * 8, vt + (j & 7) * 512);
        }
    };

    issueKV(0, 0);
#pragma unroll 2
    for (int kt = 0; kt < 32; ++kt) {
        const int cur = kt & 1;
        if (kt + 1 < 32) {
            issueKV(cur ^ 1, (kt + 1) * 64);
            BAR_WAIT_VM2;
        } else {
            BAR_WAIT_VM0;
        }
        const unsigned short* ks = KVs + cur * 8192;
        const unsigned short* vt = ks + 4096;

        // S^T = K Q^T : D[m=key][n=q]  (logits pre-scaled via Q)
        f32x4 s[2][4];
#pragma unroll
        for (int sub = 0; sub < 2; ++sub)
#pragma unroll
            for (int c = 0; c < 4; ++c) s[sub][c] = (f32x4){0.f, 0.f, 0.f, 0.f};
        __builtin_amdgcn_s_setprio(1);
#pragma unroll
        for (int ch = 0; ch < 2; ++ch) {
            const int swz = ((ch * 4 + quad) ^ swl) * 8;
#pragma unroll
            for (int c = 0; c < 4; ++c) {
                const bf16x8 aK = *(const bf16x8*)(ks + (c * 16 + l16) * 64 + swz);
#pragma unroll
                for (int sub = 0; sub < 2; ++sub)
                    s[sub][c] = __builtin_amdgcn_mfma_f32_16x16x32_bf16(
                        aK, bQ[sub][ch], s[sub][c], 0, 0, 0);
            }
        }
        __builtin_amdgcn_s_setprio(0);

        // p = 2^s (raw v_exp_f32); trunc-pack pairs (v_perm) to bf16 dwords,
        // then route S^T-layout -> PV A-fragment fully in-register.
        bf16x8 aP[2][2];
#pragma unroll
        for (int sub = 0; sub < 2; ++sub) {
            unsigned pkx[4], pky[4];
#pragma unroll
            for (int c = 0; c < 4; ++c) {
                const float p0 = EXP2F(s[sub][c][0]);
                const float p1 = EXP2F(s[sub][c][1]);
                const float p2 = EXP2F(s[sub][c][2]);
                const float p3 = EXP2F(s[sub][c][3]);
                pkx[c] = __builtin_amdgcn_perm(__float_as_uint(p1), __float_as_uint(p0), 0x07060302);
                pky[c] = __builtin_amdgcn_perm(__float_as_uint(p3), __float_as_uint(p2), 0x07060302);
            }
#pragma unroll
            for (int cc = 0; cc < 2; ++cc) {
                unsigned dx = pkx[cc * 2], ex = pkx[cc * 2 + 1];
                unsigned dy = pky[cc * 2], ey = pky[cc * 2 + 1];
                PL32(dx, ex); PL32(dy, ey);
                PL16(dx, ex); PL16(dy, ey);
                union { unsigned u[4]; bf16x8 v; } t;
                t.u[0] = dx; t.u[1] = dy; t.u[2] = ex; t.u[3] = ey;
                aP[sub][cc] = t.v;
            }
        }

        // O += P V ; l += P 1 (denominator on the MFMA pipe).
        __builtin_amdgcn_s_setprio(1);
#pragma unroll
        for (int cc = 0; cc < 2; ++cc) {
            const int swz = ((cc * 4 + quad) ^ swl) * 8;
#pragma unroll
            for (int sub = 0; sub < 2; ++sub)
                lf[sub] = __builtin_amdgcn_mfma_f32_16x16x32_bf16(aP[sub][cc], ones, lf[sub], 0, 0, 0);
#pragma unroll
            for (int et = 0; et < 4; ++et) {
                const bf16x8 bV = *(const bf16x8*)(vt + (et * 16 + l16) * 64 + swz);
#pragma unroll
                for (int sub = 0; sub < 2; ++sub)
                    o[sub][et] = __builtin_amdgcn_mfma_f32_16x16x32_bf16(
                        aP[sub][cc], bV, o[sub][et], 0, 0, 0);
            }
        }
        __builtin_amdgcn_s_setprio(0);
        BAR_WAIT_LGKM;   // all waves' ks/vt reads done before next DMA overwrites cur
    }

    // l sits in C-layout: lf[sub][r] is the denom for q-row quad*4+r (all l16).
    const int bb = bh >> 4, hh = bh & 15;
#pragma unroll
    for (int sub = 0; sub < 2; ++sub) {
#pragma unroll
        for (int r = 0; r < 4; ++r) {
            const float linv = 1.0f / lf[sub][r];
            const int qrow = q0 + wq * 32 + sub * 16 + quad * 4 + r;
#pragma unroll
            for (int et = 0; et < 4; ++et) {
                O[(size_t)(bb * 2048 + qrow) * 1024 + hh * 64 + et * 16 + l16] =
                    f2bf(o[sub][et][r] * linv);
            }
        }
    }
}

extern "C" void kernel_launch(void* const* d_in, const int* in_sizes, int n_in,
                              void* d_out, int out_size, void* d_ws, size_t ws_size,
                              hipStream_t stream) {
    const float* x     = (const float*)d_in[0];
    const float* w_q   = (const float*)d_in[1];
    const float* w_kv  = (const float*)d_in[2];
    const float* w_out = (const float*)d_in[3];
    const float* b_out = (const float*)d_in[4];
    const float CEXP = 0.125f * 1.44269504f;   // attn scale * log2(e), folded into w_q
    const size_t MB = 1024 * 1024;

    // ws (64 MB): Qw@0 16 | Kw@16 16 | Vw@32 16 | Ow@48 16   (all bf16)
    // d_out (32 MB fp32, dead until final GEMM): xb@0 16 | wqkvb@16 6 (bf16).
    // wob (w_out bf16, 2 MB) -> dead Qw region AFTER attn.
    unsigned short* Qw    = (unsigned short*)d_ws;
    unsigned short* Kw    = (unsigned short*)((char*)d_ws + 16 * MB);
    unsigned short* Vw    = (unsigned short*)((char*)d_ws + 32 * MB);
    unsigned short* Ow    = (unsigned short*)((char*)d_ws + 48 * MB);
    unsigned short* xb    = (unsigned short*)d_out;
    unsigned short* wqkvb = (unsigned short*)((char*)d_out + 16 * MB);
    unsigned short* wob   = Qw;

    // Convert x + packed [w_q (pre-scaled); w_kv] to bf16 in d_out scratch.
    convert_regions<<<5632, 256, 0, stream>>>(
        x, xb, 8388608, 1.0f,
        w_q, wqkvb, 1048576, CEXP,
        w_kv, wqkvb + (size_t)1048576, 2097152, 1.0f);

    // Fused QKV projection: 256^2 tile, 512 threads, dim3(32,12) = 384 blocks.
    gemm256_qkv<<<dim3(32, 12), 512, 0, stream>>>(
        xb, wqkvb, Qw, Kw, Vw, 8192, 3072, 1024);

    // Attention: 512 blocks dim3(8,64), 512 threads (8 waves x 32 q).
    attn_kernel<<<dim3(8, 64), 512, 0, stream>>>(Qw, Kw, Vw, Ow);

    // w_out -> bf16 into dead Qw region.
    convert_regions<<<512, 256, 0, stream>>>(
        w_out, wob, 1048576, 1.0f,
        nullptr, nullptr, 0, 0.f, nullptr, nullptr, 0, 0.f);

    // Out projection, 128^2 tile (proven), dim3 grid; writes fp32 d_out.
    gemm128_bias<<<dim3(64, 8), 256, 0, stream>>>(
        Ow, wob, (float*)d_out, b_out, 8192, 1024, 1024);
}

// Round 13
// 591.048 us; speedup vs baseline: 1.0036x; 1.0008x over previous
//
#include <hip/hip_runtime.h>

typedef __attribute__((ext_vector_type(8))) short bf16x8;
typedef __attribute__((ext_vector_type(4))) float f32x4;

#define AS1 __attribute__((address_space(1)))
#define AS3 __attribute__((address_space(3)))

#if defined(__has_builtin)
#  if __has_builtin(__builtin_amdgcn_exp2f)
#    define EXP2F(x) __builtin_amdgcn_exp2f(x)
#  endif
#endif
#ifndef EXP2F
#  define EXP2F(x) __builtin_exp2f(x)
#endif

// Raw barriers that do NOT drain the async prefetch queue (unlike __syncthreads,
// which emits s_waitcnt vmcnt(0) lgkmcnt(0) and kills the pipeline).
#define BAR_WAIT_VM8  asm volatile("s_waitcnt vmcnt(8)\ns_barrier" ::: "memory")
#define BAR_WAIT_VM4  asm volatile("s_waitcnt vmcnt(4)\ns_barrier" ::: "memory")
#define BAR_WAIT_VM2  asm volatile("s_waitcnt vmcnt(2)\ns_barrier" ::: "memory")
#define BAR_WAIT_VM0  asm volatile("s_waitcnt vmcnt(0)\ns_barrier" ::: "memory")
#define BAR_WAIT_LGKM asm volatile("s_waitcnt lgkmcnt(0)\ns_barrier" ::: "memory")

// gfx950 dual-swap lane exchanges (both operands updated):
//   permlane32: a' = [a.lo32 | b.lo32], b' = [a.hi32 | b.hi32]
//   permlane16: 16-lane rows: a' = [a.r0, b.r0, a.r2, b.r2], b' = [a.r1, b.r1, a.r3, b.r3]
#define PL32(a, b) asm("v_permlane32_swap_b32 %0, %1" : "+v"(a), "+v"(b))
#define PL16(a, b) asm("v_permlane16_swap_b32 %0, %1" : "+v"(a), "+v"(b))

__device__ __forceinline__ unsigned short f2bf(float f) {
    union { float f; unsigned u; } v; v.f = f;
    unsigned r = v.u + 0x7fffu + ((v.u >> 16) & 1u);   // RNE
    return (unsigned short)(r >> 16);
}

// Async 16B/lane global->LDS DMA. lds dst must be wave-uniform base (+lane*16).
__device__ __forceinline__ void dma16(const void* g, void* l) {
    __builtin_amdgcn_global_load_lds((const AS1 unsigned int*)g,
                                     (AS3 unsigned int*)l, 16, 0, 0);
}

// fp32 -> bf16 bulk convert, up to 3 regions, optional scale. 8 elems/thread.
__global__ __launch_bounds__(256) void convert_regions(
    const float* __restrict__ s0, unsigned short* __restrict__ d0, int n0, float c0,
    const float* __restrict__ s1, unsigned short* __restrict__ d1, int n1, float c1,
    const float* __restrict__ s2, unsigned short* __restrict__ d2, int n2, float c2)
{
    long long e = ((long long)blockIdx.x * 256 + threadIdx.x) * 8;
    const float* s; unsigned short* d; float sc;
    if (e < n0) { s = s0; d = d0; sc = c0; }
    else { e -= n0;
    if (e < n1) { s = s1; d = d1; sc = c1; }
    else { e -= n1;
    if (e < n2) { s = s2; d = d2; sc = c2; } else return; } }
    const float4 f0 = *(const float4*)(s + e);
    const float4 f1 = *(const float4*)(s + e + 4);
    union { unsigned short u[8]; uint4 q; } t;
    t.u[0]=f2bf(f0.x*sc); t.u[1]=f2bf(f0.y*sc); t.u[2]=f2bf(f0.z*sc); t.u[3]=f2bf(f0.w*sc);
    t.u[4]=f2bf(f1.x*sc); t.u[5]=f2bf(f1.y*sc); t.u[6]=f2bf(f1.z*sc); t.u[7]=f2bf(f1.w*sc);
    *(uint4*)(d + e) = t.q;
}

// ---------------------------------------------------------------------------
// GEMM 128x128 (out-projection): C = A[M,K] * B[N,K]^T + bias, fp32 out.
// 4 waves (2x2), 4x4 16x16x32 MFMA/wave, global_load_lds staging,
// XOR-swizzled unpadded LDS, double-buffered raw-barrier K-loop
// (vmcnt(8) keeps prefetch in flight; lgkm read-fence only at end).
// LDS 64 KB -> 2 blocks/CU. NO min-blocks launch_bounds (spill cliff).
// ---------------------------------------------------------------------------
__global__ __launch_bounds__(256) void gemm128_bias(
    const unsigned short* __restrict__ A, const unsigned short* __restrict__ B,
    float* __restrict__ C0, const float* __restrict__ bias, int M, int N, int K)
{
    __shared__ __align__(16) unsigned short smem[2 * 16384];

    const int tid  = threadIdx.x;
    const int wq   = tid >> 6;
    const int lane = tid & 63;
    const int l16  = lane & 15;
    const int quad = lane >> 4;
    const int m0   = blockIdx.x * 128;
    const int n0   = blockIdx.y * 128;
    const int lr   = lane >> 3;
    const int cs   = lane & 7;

    f32x4 acc[4][4];
#pragma unroll
    for (int mt = 0; mt < 4; ++mt)
#pragma unroll
        for (int nt = 0; nt < 4; ++nt) acc[mt][nt] = (f32x4){0.f, 0.f, 0.f, 0.f};

    auto issue = [&](int buf, int kk) {
        unsigned short* as = smem + buf * 16384;
        unsigned short* bs = as + 8192;
#pragma unroll
        for (int i = 0; i < 4; ++i) {
            const int rr = (wq * 4 + i) * 8 + lr;
            const int cg = cs ^ (rr & 7);
            dma16(A + (size_t)(m0 + rr) * K + kk + cg * 8, as + (wq * 4 + i) * 512);
            dma16(B + (size_t)(n0 + rr) * K + kk + cg * 8, bs + (wq * 4 + i) * 512);
        }
    };

    const int nIt = K >> 6;
    issue(0, 0);
#pragma unroll 2
    for (int it = 0; it < nIt; ++it) {
        const int cur = it & 1;
        if (it + 1 < nIt) {
            issue(cur ^ 1, (it + 1) << 6);
            BAR_WAIT_VM8;
        } else {
            BAR_WAIT_VM0;
        }
        const unsigned short* as = smem + cur * 16384;
        const unsigned short* bs = as + 8192;
#pragma unroll
        for (int ch = 0; ch < 2; ++ch) {
            const int swz = (((ch * 4 + quad) ^ (l16 & 7)) * 8);
            bf16x8 aF[4], bF[4];
#pragma unroll
            for (int mt = 0; mt < 4; ++mt)
                aF[mt] = *(const bf16x8*)(as + ((wq >> 1) * 64 + mt * 16 + l16) * 64 + swz);
#pragma unroll
            for (int nt = 0; nt < 4; ++nt)
                bF[nt] = *(const bf16x8*)(bs + ((wq & 1) * 64 + nt * 16 + l16) * 64 + swz);
#pragma unroll
            for (int mt = 0; mt < 4; ++mt)
#pragma unroll
                for (int nt = 0; nt < 4; ++nt)
                    acc[mt][nt] = __builtin_amdgcn_mfma_f32_16x16x32_bf16(
                        aF[mt], bF[nt], acc[mt][nt], 0, 0, 0);
        }
        BAR_WAIT_LGKM;
    }

    const int wr = wq >> 1, wc = wq & 1;
#pragma unroll
    for (int mt = 0; mt < 4; ++mt)
#pragma unroll
    for (int nt = 0; nt < 4; ++nt) {
        const int coln = n0 + wc * 64 + nt * 16 + l16;
        const float bv = bias ? bias[coln] : 0.f;
#pragma unroll
        for (int r = 0; r < 4; ++r) {
            const int rowm = m0 + wr * 64 + mt * 16 + quad * 4 + r;
            C0[(size_t)rowm * N + coln] = acc[mt][nt][r] + bv;
        }
    }
}

// ---------------------------------------------------------------------------
// ROUND 13: GEMM 256x256 (fused QKV) — THIRD attempt, with the REAL register
// knob. R11/R12 evidence pinned down that hipcc's __launch_bounds__ 2nd arg
// behaves as CUDA-style MIN BLOCKS PER CU here (NOT min-waves/EU):
//   attn (512,4)   -> VGPR cap  64 = 512/(4 blk * 8 waves / 4 SIMD)  [obs 64]
//   gemm256 (512,2)-> VGPR cap 128 = 512/(2 * 8 / 4)                 [obs 128]
// Under waves/EU semantics the caps would have been 128/256 — falsified.
// FIX: __launch_bounds__(512, 1): 1 block/CU (which the 128 KB LDS forces
// anyway) -> 2 waves/EU -> VGPR cap 256, above the ~210 this kernel needs
// (acc 128 + aF 32 + bF 16 + addressing). R12's 930 MB WRITE_SIZE was acc
// streaming to scratch (FETCH stayed at the no-spill 354 MB — write-out
// without reload ballooning).
// Staging-economy rationale unchanged: bytes-staged/FLOP halves vs 128^2
// (15.2 -> 7.6 B/KFLOP) on the staging-bandwidth-bound proven loop.
// 512 threads = 8 waves (2M x 4N); wave owns 128x64 = 8x4 16x16x32 frags.
// Grid dim3(32,12) = 384 blocks. Epilogue over N=3072: cols 0..1023 -> Q
// [bh][n][e] (C0), 1024..2047 -> K (C1), 2048..3071 -> V^T [bh][e][n]
// (C2, transposed tile via mfma(bF,aF)).
// ---------------------------------------------------------------------------
__global__ __launch_bounds__(512, 1) void gemm256_qkv(
    const unsigned short* __restrict__ A, const unsigned short* __restrict__ B,
    unsigned short* __restrict__ C0, unsigned short* __restrict__ C1,
    unsigned short* __restrict__ C2, int M, int N, int K)
{
    __shared__ __align__(16) unsigned short smem[2 * 32768];   // 128 KB

    const int tid  = threadIdx.x;
    const int wq   = tid >> 6;          // 0..7
    const int lane = tid & 63;
    const int l16  = lane & 15;
    const int quad = lane >> 4;
    const int m0   = blockIdx.x * 256;
    const int n0   = blockIdx.y * 256;
    const int lr   = lane >> 3;
    const int cs   = lane & 7;
    const int wr   = wq >> 2;           // 0..1 (M half)
    const int wc   = wq & 3;            // 0..3 (N quarter)
    const bool vswap = (n0 >= 2048);

    f32x4 acc[8][4];
#pragma unroll
    for (int mt = 0; mt < 8; ++mt)
#pragma unroll
        for (int nt = 0; nt < 4; ++nt) acc[mt][nt] = (f32x4){0.f, 0.f, 0.f, 0.f};

    // Stage A[256x64] + B[256x64] (32 KB each): 8 waves x 4 chunks x 8 rows.
    auto issue = [&](int buf, int kk) {
        unsigned short* as = smem + buf * 32768;
        unsigned short* bs = as + 16384;
#pragma unroll
        for (int i = 0; i < 4; ++i) {
            const int rr = (wq * 4 + i) * 8 + lr;       // 0..255
            const int cg = cs ^ (rr & 7);
            dma16(A + (size_t)(m0 + rr) * K + kk + cg * 8, as + (wq * 4 + i) * 512);
            dma16(B + (size_t)(n0 + rr) * K + kk + cg * 8, bs + (wq * 4 + i) * 512);
        }
    };

    const int nIt = K >> 6;
    issue(0, 0);
#pragma unroll 2
    for (int it = 0; it < nIt; ++it) {
        const int cur = it & 1;
        if (it + 1 < nIt) {
            issue(cur ^ 1, (it + 1) << 6);
            BAR_WAIT_VM8;       // waits only current tile's 8 DMAs/wave
        } else {
            BAR_WAIT_VM0;
        }
        const unsigned short* as = smem + cur * 32768;
        const unsigned short* bs = as + 16384;
#pragma unroll
        for (int ch = 0; ch < 2; ++ch) {
            const int swz = (((ch * 4 + quad) ^ (l16 & 7)) * 8);
            bf16x8 aF[8], bF[4];
#pragma unroll
            for (int mt = 0; mt < 8; ++mt)
                aF[mt] = *(const bf16x8*)(as + (wr * 128 + mt * 16 + l16) * 64 + swz);
#pragma unroll
            for (int nt = 0; nt < 4; ++nt)
                bF[nt] = *(const bf16x8*)(bs + (wc * 64 + nt * 16 + l16) * 64 + swz);
            if (vswap) {
#pragma unroll
                for (int mt = 0; mt < 8; ++mt)
#pragma unroll
                    for (int nt = 0; nt < 4; ++nt)
                        acc[mt][nt] = __builtin_amdgcn_mfma_f32_16x16x32_bf16(
                            bF[nt], aF[mt], acc[mt][nt], 0, 0, 0);
            } else {
#pragma unroll
                for (int mt = 0; mt < 8; ++mt)
#pragma unroll
                    for (int nt = 0; nt < 4; ++nt)
                        acc[mt][nt] = __builtin_amdgcn_mfma_f32_16x16x32_bf16(
                            aF[mt], bF[nt], acc[mt][nt], 0, 0, 0);
            }
        }
        BAR_WAIT_LGKM;
    }

    if (!vswap) {
        // Q (cols<1024) / K (1024..2047): [bh][n][e]
#pragma unroll
        for (int mt = 0; mt < 8; ++mt)
#pragma unroll
        for (int nt = 0; nt < 4; ++nt) {
            const int coln = n0 + wc * 64 + nt * 16 + l16;
            unsigned short* dst = (coln < 1024) ? C0 : C1;
            const int h = (coln >> 6) & 15, e = coln & 63;
#pragma unroll
            for (int r = 0; r < 4; ++r) {
                const int rowm = m0 + wr * 128 + mt * 16 + quad * 4 + r;
                const int b = rowm >> 11, n = rowm & 2047;
                dst[(((size_t)(b * 16 + h) * 2048 + n) << 6) + e] = f2bf(acc[mt][nt][r]);
            }
        }
    } else {
        // V^T: acc holds transposed tile; rows = V-cols (e), cols = tokens.
#pragma unroll
        for (int mt = 0; mt < 8; ++mt)
#pragma unroll
        for (int nt = 0; nt < 4; ++nt) {
#pragma unroll
            for (int r = 0; r < 4; ++r) {
                const int eg = n0 + wc * 64 + nt * 16 + quad * 4 + r;  // 2048..3071
                const int h = (eg >> 6) - 32, e = eg & 63;
                const int rowm = m0 + wr * 128 + mt * 16 + l16;
                const int b = rowm >> 11, n = rowm & 2047;
                C2[((size_t)(b * 16 + h) * 64 + e) * 2048 + n] = f2bf(acc[mt][nt][r]);
            }
        }
    }
}

// ---------------------------------------------------------------------------
// Flash attention — R9 version (best measured: 74.8 us). R3 structure +
// T5 setprio around the two MFMA clusters (+5.3% verified, m191-consistent).
// Q,K: [bh][n][e] bf16 (Q pre-scaled by 0.125*log2e); V: [bh][e][n] bf16.
// O: [b*n][1024] bf16. Block = 512 threads = 8 waves x 32 q-rows.
// Double-buffered raw-barrier K/V staging (vmcnt(2)); Ps LDS eliminated
// (in-register PL32/PL16 relayout); LDS 32 KB.
// NOTE launch_bounds (512,4): under the CUDA-style min-BLOCKS semantics
// established in R12, this caps VGPR at 64 (4 blk x 8 waves / 4 SIMD = 8
// waves/EU). Measured VGPR=64, no spill — keep as-is.
// ---------------------------------------------------------------------------
__global__ __launch_bounds__(512, 4) void attn_kernel(
    const unsigned short* __restrict__ Q, const unsigned short* __restrict__ K,
    const unsigned short* __restrict__ V, unsigned short* __restrict__ O)
{
    __shared__ __align__(16) unsigned short KVs[2 * 8192];  // [buf][Ks 4096|Vt 4096]

    const int tid  = threadIdx.x;
    const int q0   = blockIdx.x * 256;
    const int bh   = blockIdx.y;
    const int wq   = tid >> 6;          // 0..7
    const int lane = tid & 63;
    const int l16  = lane & 15;
    const int quad = lane >> 4;
    const int lr   = lane >> 3;
    const int cs   = lane & 7;
    const int swl  = l16 & 7;           // row-XOR for the K/V tile swizzle

    const unsigned short* Qg = Q + (size_t)bh * 2048 * 64;
    const unsigned short* Kg = K + (size_t)bh * 2048 * 64;
    const unsigned short* Vg = V + (size_t)bh * 64 * 2048;

    bf16x8 bQ[2][2];
#pragma unroll
    for (int sub = 0; sub < 2; ++sub)
#pragma unroll
        for (int ch = 0; ch < 2; ++ch)
            bQ[sub][ch] = *(const bf16x8*)(Qg + (size_t)(q0 + wq * 32 + sub * 16 + l16) * 64
                                           + ch * 32 + quad * 8);

    bf16x8 ones;
#pragma unroll
    for (int i = 0; i < 8; ++i) ones[i] = (short)0x3F80;  // bf16 1.0

    f32x4 o[2][4], lf[2];
#pragma unroll
    for (int s = 0; s < 2; ++s) {
        lf[s] = (f32x4){0.f, 0.f, 0.f, 0.f};
#pragma unroll
        for (int e = 0; e < 4; ++e) o[s][e] = (f32x4){0.f, 0.f, 0.f, 0.f};
    }

    auto issueKV = [&](int buf, int key0) {
        unsigned short* ks = KVs + buf * 8192;
        unsigned short* vt = ks + 4096;
#pragma unroll
        for (int i = 0; i < 2; ++i) {
            const int j  = wq * 2 + i;          // 0..15
            const int rr = (j & 7) * 8 + lr;
            const int cg = cs ^ (rr & 7);
            if (j < 8)
                dma16(Kg + (size_t)(key0 + rr) * 64 + cg * 8, ks + (j & 7) * 512);
            else
                dma16(Vg + (size_t)rr * 2048 + key0 + cg * 8, vt + (j & 7) * 512);
        }
    };

    issueKV(0, 0);
#pragma unroll 2
    for (int kt = 0; kt < 32; ++kt) {
        const int cur = kt & 1;
        if (kt + 1 < 32) {
            issueKV(cur ^ 1, (kt + 1) * 64);
            BAR_WAIT_VM2;
        } else {
            BAR_WAIT_VM0;
        }
        const unsigned short* ks = KVs + cur * 8192;
        const unsigned short* vt = ks + 4096;

        // S^T = K Q^T : D[m=key][n=q]  (logits pre-scaled via Q)
        f32x4 s[2][4];
#pragma unroll
        for (int sub = 0; sub < 2; ++sub)
#pragma unroll
            for (int c = 0; c < 4; ++c) s[sub][c] = (f32x4){0.f, 0.f, 0.f, 0.f};
        __builtin_amdgcn_s_setprio(1);
#pragma unroll
        for (int ch = 0; ch < 2; ++ch) {
            const int swz = ((ch * 4 + quad) ^ swl) * 8;
#pragma unroll
            for (int c = 0; c < 4; ++c) {
                const bf16x8 aK = *(const bf16x8*)(ks + (c * 16 + l16) * 64 + swz);
#pragma unroll
                for (int sub = 0; sub < 2; ++sub)
                    s[sub][c] = __builtin_amdgcn_mfma_f32_16x16x32_bf16(
                        aK, bQ[sub][ch], s[sub][c], 0, 0, 0);
            }
        }
        __builtin_amdgcn_s_setprio(0);

        // p = 2^s (raw v_exp_f32); trunc-pack pairs (v_perm) to bf16 dwords,
        // then route S^T-layout -> PV A-fragment fully in-register.
        bf16x8 aP[2][2];
#pragma unroll
        for (int sub = 0; sub < 2; ++sub) {
            unsigned pkx[4], pky[4];
#pragma unroll
            for (int c = 0; c < 4; ++c) {
                const float p0 = EXP2F(s[sub][c][0]);
                const float p1 = EXP2F(s[sub][c][1]);
                const float p2 = EXP2F(s[sub][c][2]);
                const float p3 = EXP2F(s[sub][c][3]);
                pkx[c] = __builtin_amdgcn_perm(__float_as_uint(p1), __float_as_uint(p0), 0x07060302);
                pky[c] = __builtin_amdgcn_perm(__float_as_uint(p3), __float_as_uint(p2), 0x07060302);
            }
#pragma unroll
            for (int cc = 0; cc < 2; ++cc) {
                unsigned dx = pkx[cc * 2], ex = pkx[cc * 2 + 1];
                unsigned dy = pky[cc * 2], ey = pky[cc * 2 + 1];
                PL32(dx, ex); PL32(dy, ey);
                PL16(dx, ex); PL16(dy, ey);
                union { unsigned u[4]; bf16x8 v; } t;
                t.u[0] = dx; t.u[1] = dy; t.u[2] = ex; t.u[3] = ey;
                aP[sub][cc] = t.v;
            }
        }

        // O += P V ; l += P 1 (denominator on the MFMA pipe).
        __builtin_amdgcn_s_setprio(1);
#pragma unroll
        for (int cc = 0; cc < 2; ++cc) {
            const int swz = ((cc * 4 + quad) ^ swl) * 8;
#pragma unroll
            for (int sub = 0; sub < 2; ++sub)
                lf[sub] = __builtin_amdgcn_mfma_f32_16x16x32_bf16(aP[sub][cc], ones, lf[sub], 0, 0, 0);
#pragma unroll
            for (int et = 0; et < 4; ++et) {
                const bf16x8 bV = *(const bf16x8*)(vt + (et * 16 + l16) * 64 + swz);
#pragma unroll
                for (int sub = 0; sub < 2; ++sub)
                    o[sub][et] = __builtin_amdgcn_mfma_f32_16x16x32_bf16(
                        aP[sub][cc], bV, o[sub][et], 0, 0, 0);
            }
        }
        __builtin_amdgcn_s_setprio(0);
        BAR_WAIT_LGKM;   // all waves' ks/vt reads done before next DMA overwrites cur
    }

    // l sits in C-layout: lf[sub][r] is the denom for q-row quad*4+r (all l16).
    const int bb = bh >> 4, hh = bh & 15;
#pragma unroll
    for (int sub = 0; sub < 2; ++sub) {
#pragma unroll
        for (int r = 0; r < 4; ++r) {
            const float linv = 1.0f / lf[sub][r];
            const int qrow = q0 + wq * 32 + sub * 16 + quad * 4 + r;
#pragma unroll
            for (int et = 0; et < 4; ++et) {
                O[(size_t)(bb * 2048 + qrow) * 1024 + hh * 64 + et * 16 + l16] =
                    f2bf(o[sub][et][r] * linv);
            }
        }
    }
}

extern "C" void kernel_launch(void* const* d_in, const int* in_sizes, int n_in,
                              void* d_out, int out_size, void* d_ws, size_t ws_size,
                              hipStream_t stream) {
    const float* x     = (const float*)d_in[0];
    const float* w_q   = (const float*)d_in[1];
    const float* w_kv  = (const float*)d_in[2];
    const float* w_out = (const float*)d_in[3];
    const float* b_out = (const float*)d_in[4];
    const float CEXP = 0.125f * 1.44269504f;   // attn scale * log2(e), folded into w_q
    const size_t MB = 1024 * 1024;

    // ws (64 MB): Qw@0 16 | Kw@16 16 | Vw@32 16 | Ow@48 16   (all bf16)
    // d_out (32 MB fp32, dead until final GEMM): xb@0 16 | wqkvb@16 6 (bf16).
    // wob (w_out bf16, 2 MB) -> dead Qw region AFTER attn.
    unsigned short* Qw    = (unsigned short*)d_ws;
    unsigned short* Kw    = (unsigned short*)((char*)d_ws + 16 * MB);
    unsigned short* Vw    = (unsigned short*)((char*)d_ws + 32 * MB);
    unsigned short* Ow    = (unsigned short*)((char*)d_ws + 48 * MB);
    unsigned short* xb    = (unsigned short*)d_out;
    unsigned short* wqkvb = (unsigned short*)((char*)d_out + 16 * MB);
    unsigned short* wob   = Qw;

    // Convert x + packed [w_q (pre-scaled); w_kv] to bf16 in d_out scratch.
    convert_regions<<<5632, 256, 0, stream>>>(
        x, xb, 8388608, 1.0f,
        w_q, wqkvb, 1048576, CEXP,
        w_kv, wqkvb + (size_t)1048576, 2097152, 1.0f);

    // Fused QKV projection: 256^2 tile, 512 threads, dim3(32,12) = 384 blocks.
    gemm256_qkv<<<dim3(32, 12), 512, 0, stream>>>(
        xb, wqkvb, Qw, Kw, Vw, 8192, 3072, 1024);

    // Attention: 512 blocks dim3(8,64), 512 threads (8 waves x 32 q).
    attn_kernel<<<dim3(8, 64), 512, 0, stream>>>(Qw, Kw, Vw, Ow);

    // w_out -> bf16 into dead Qw region.
    convert_regions<<<512, 256, 0, stream>>>(
        w_out, wob, 1048576, 1.0f,
        nullptr, nullptr, 0, 0.f, nullptr, nullptr, 0, 0.f);

    // Out projection, 128^2 tile (proven), dim3 grid; writes fp32 d_out.
    gemm128_bias<<<dim3(64, 8), 256, 0, stream>>>(
        Ow, wob, (float*)d_out, b_out, 8192, 1024, 1024);
}